// Round 8
// baseline (281.204 us; speedup 1.0000x reference)
//
#include <hip/hip_runtime.h>
#include <hip/hip_cooperative_groups.h>
#include <stdint.h>

namespace cg = cooperative_groups;

#define N_ANCH  65648
#define NCHUNK  32          // chunks per batch
#define CHUNKSZ 2052        // 32*2052 = 65664 >= 65648 (last chunk short)
#define UMAX    9           // ceil(2052/256)
#define CAP     2048        // per-batch candidate list capacity
#define KBASE   0xBE800000u // sortable key of 0.25; fg scores >= 1/3 -> bins in [42,255]
#define NBATCH  32
#define TOPK    100
#define GRID    (NBATCH * NCHUNK)   // 1024 = 4 blocks/CU exactly

struct Ptrs { const float* cls[8]; const float* reg[8]; };

__constant__ int   c_off[9] = {0,25281,50562,56803,63044,64565,64926,65287,65648};
__constant__ int   c_sz[8]  = {159,159,79,79,39,19,19,19};
__constant__ float c_st[8]  = {4.f,4.f,8.f,8.f,16.f,32.f,32.f,32.f};
__constant__ float c_rf[8]  = {27.5f,35.5f,55.5f,71.5f,111.5f,191.5f,255.5f,319.5f};

// sortable key for the masked score of anchor n in batch b; 0 if background.
// EXACT same fp sequence as all passing rounds.
__device__ inline uint32_t anchor_key(const Ptrs& p, int b, int n) {
  int k = 0;
#pragma unroll
  for (int q = 1; q < 8; ++q) if (n >= c_off[q]) k = q;
  int local = n - c_off[k];
  int hw = c_sz[k] * c_sz[k];
  const float* c = p.cls[k] + (size_t)(b * 3) * hw + local;
  float l0 = c[0], l1 = c[(size_t)hw], l2 = c[(size_t)2 * hw];
  float m = l0; int cl = 0;
  if (l1 > m) { m = l1; cl = 1; }
  if (l2 > m) { m = l2; cl = 2; }
  if (cl == 0) return 0u;
  float s = 1.0f / (expf(l0 - m) + expf(l1 - m) + expf(l2 - m));
  return __float_as_uint(s) | 0x80000000u; // positive float -> monotonic uint
}

// rank-selection: thread owns candidates t, t+256, ...; ranks vs all c via
// conflict-free LDS broadcast reads; rank<TOPK scatters into top[rank].
template<int U>
__device__ inline void rank_select(const unsigned long long* s_all, int c, int t,
                                   unsigned long long* top) {
  unsigned long long mine[U]; int rk[U];
#pragma unroll
  for (int u = 0; u < U; ++u) {
    int i = t + u * 256;
    mine[u] = (i < c) ? s_all[i] : 0ull;
    rk[u] = 0;
  }
  for (int j = 0; j < c; ++j) {
    unsigned long long v = s_all[j];
#pragma unroll
    for (int u = 0; u < U; ++u) rk[u] += (v > mine[u]) ? 1 : 0;
  }
#pragma unroll
  for (int u = 0; u < U; ++u) {
    int i = t + u * 256;
    if (i < c && rk[u] < TOPK) top[rk[u]] = mine[u];   // unique u64s -> unique ranks
  }
}

__global__ __launch_bounds__(256, 4) void lffd_all(Ptrs p, uint16_t* hist,
                                                   uint32_t* counter,
                                                   unsigned long long* cand, float* out) {
  cg::grid_group grid = cg::this_grid();
  int bid = blockIdx.x, t = threadIdx.x;
  int b = bid / NCHUNK, chunk = bid % NCHUNK;

  __shared__ uint32_t lh[256];
  __shared__ uint32_t tot[256];
  __shared__ unsigned long long stage[CHUNKSZ];   // 16.4 KB; reused as s_all in D
  __shared__ unsigned long long top[TOPK];
  __shared__ float bx1[TOPK], by1[TOPK], bx2[TOPK], by2[TOPK], area[TOPK], sc[TOPK];
  __shared__ int cls_s[TOPK], keep[TOPK];
  __shared__ uint32_t s_cnt, s_base;
  __shared__ int s_thr;

  // ---- Phase A: keys in registers + per-(batch,chunk) histogram ----
  uint32_t myk[UMAX];
  int nbase = chunk * CHUNKSZ;
  lh[t] = 0;
  if (chunk == 0 && t == 0) counter[b] = 0;     // ordered before phase C by grid.sync
  __syncthreads();
#pragma unroll
  for (int u = 0; u < UMAX; ++u) {
    int idx = u * 256 + t;
    int n = nbase + idx;
    uint32_t key = 0;
    if (idx < CHUNKSZ && n < N_ANCH) key = anchor_key(p, b, n);
    myk[u] = key;
    if (key >= KBASE) atomicAdd(&lh[(key - KBASE) >> 16], 1u);   // LDS only
  }
  __syncthreads();
  hist[((size_t)b * NCHUNK + chunk) * 256 + t] = (uint16_t)lh[t];

  grid.sync();

  // ---- Phase B: redundant per-block threshold (32 coalesced u16 rounds) ----
  {
    const uint16_t* hb = hist + (size_t)b * NCHUNK * 256;
    uint32_t v = 0;
#pragma unroll 4
    for (int ch = 0; ch < NCHUNK; ++ch) v += hb[ch * 256 + t];
    tot[t] = v;
    if (t == 0) s_cnt = 0;
    __syncthreads();
    for (int d = 1; d < 256; d <<= 1) {          // inclusive suffix sum
      uint32_t add = (t + d < 256) ? tot[t + d] : 0u;
      __syncthreads();
      tot[t] += add;
      __syncthreads();
    }
    uint32_t suf = tot[t], sufn = (t < 255) ? tot[t + 1] : 0u;
    if (suf >= TOPK && sufn < TOPK) s_thr = t;   // exactly one setter
    if (t == 0 && tot[0] < TOPK) s_thr = 0;
    __syncthreads();
  }
  int thr = s_thr; if (thr < 1) thr = 1;         // bin>=1 <=> foreground
  uint32_t thkey = KBASE + ((uint32_t)thr << 16);

  // ---- Phase C: compact candidates from registers (1 global atomic/block) ----
#pragma unroll
  for (int u = 0; u < UMAX; ++u) {
    uint32_t key = myk[u];
    if (key >= thkey) {                          // key==0 for invalid anchors
      int n = nbase + u * 256 + t;
      uint32_t pos = atomicAdd(&s_cnt, 1u);      // LDS; pos < CHUNKSZ always
      stage[pos] = ((unsigned long long)key << 32) | (uint32_t)(~(uint32_t)n);
    }
  }
  __syncthreads();
  if (t == 0) s_base = atomicAdd(&counter[b], s_cnt);
  __syncthreads();
  {
    uint32_t cnt = s_cnt, base = s_base;
    for (uint32_t j = t; j < cnt; j += 256) {
      uint32_t g = base + j;
      if (g < CAP) cand[(size_t)b * CAP + g] = stage[j];  // coalesced
    }
  }

  grid.sync();

  // ---- Phase D: 32 blocks, strictly O(CAP): rank-select, decode, NMS, out ----
  if (bid < NBATCH) {
    int bb = bid;
    int c = (int)min(counter[bb], (uint32_t)CAP);
    for (int i = t; i < c; i += 256) stage[i] = cand[(size_t)bb * CAP + i];
    if (t < TOPK) top[t] = 0ull;
    __syncthreads();

    if      (c <= 256)  rank_select<1>(stage, c, t, top);
    else if (c <= 512)  rank_select<2>(stage, c, t, top);
    else if (c <= 1024) rank_select<4>(stage, c, t, top);
    else                rank_select<8>(stage, c, t, top);
    __syncthreads();

    int r = t;
    if (r < TOPK) {
      unsigned long long pk = top[r];
      if (pk == 0ull) {
        sc[r] = -1.f; cls_s[r] = 0; keep[r] = 0;
        bx1[r] = by1[r] = bx2[r] = by2[r] = 0.f; area[r] = 1.f;
      } else {
        uint32_t key = (uint32_t)(pk >> 32);
        int n = (int)(~(uint32_t)pk);
        float score = __uint_as_float(key & 0x7FFFFFFFu);
        int k2 = 0;
#pragma unroll
        for (int q = 1; q < 8; ++q) if (n >= c_off[q]) k2 = q;
        int local = n - c_off[k2];
        int w = c_sz[k2], hw = w * w;
        int i2 = local / w, j2 = local % w;
        const float* cp = p.cls[k2] + (size_t)(bb * 3) * hw + local;
        float l0 = cp[0], l1 = cp[(size_t)hw], l2 = cp[(size_t)2 * hw];
        float m = l0; int cl = 0;
        if (l1 > m) { m = l1; cl = 1; }
        if (l2 > m) { m = l2; cl = 2; }
        const float* rp = p.reg[k2] + (size_t)(bb * 4) * hw + local;
        float r0 = rp[0], r1 = rp[(size_t)hw], r2 = rp[(size_t)2 * hw], r3 = rp[(size_t)3 * hw];
        float st = c_st[k2], rf = c_rf[k2];
        float cx = (float)j2 * st + st * 0.5f;
        float cy = (float)i2 * st + st * 0.5f;
        float x1 = cx - r0 * rf, y1 = cy - r1 * rf;
        float x2 = cx + r2 * rf, y2 = cy + r3 * rf;
        sc[r] = score; cls_s[r] = cl;
        bx1[r] = x1; by1[r] = y1; bx2[r] = x2; by2[r] = y2;
        area[r] = (x2 - x1 + 1.0f) * (y2 - y1 + 1.0f);
        keep[r] = (score >= 0.35f && cl > 0) ? 1 : 0;
      }
    }
    __syncthreads();

    // greedy NMS in a single wave: lane l owns ranks l and l+64; zero barriers
    if (t < 64) {
      int r0 = t, r1 = t + 64;
      float a1x = bx1[r0], a1y = by1[r0], a2x = bx2[r0], a2y = by2[r0], aA = area[r0];
      int k0 = keep[r0];
      bool has1 = (r1 < TOPK);
      float c1x = 0.f, c1y = 0.f, c2x = 0.f, c2y = 0.f, cA = 1.f;
      int k1 = 0;
      if (has1) { c1x = bx1[r1]; c1y = by1[r1]; c2x = bx2[r1]; c2y = by2[r1]; cA = area[r1]; k1 = keep[r1]; }
      for (int i = 0; i < TOPK; ++i) {
        int ol = i & 63, sl = i >> 6;
        int   ki  = __shfl(sl ? k1  : k0,  ol);
        float ix1 = __shfl(sl ? c1x : a1x, ol);
        float iy1 = __shfl(sl ? c1y : a1y, ol);
        float ix2 = __shfl(sl ? c2x : a2x, ol);
        float iy2 = __shfl(sl ? c2y : a2y, ol);
        float iA  = __shfl(sl ? cA  : aA,  ol);
        if (ki) {
          if (k0 && r0 > i) {
            float xmin = fmaxf(ix1, a1x), ymin = fmaxf(iy1, a1y);
            float xmax = fminf(ix2, a2x), ymax = fminf(iy2, a2y);
            float inter = fmaxf(xmax - xmin, 0.f) * fmaxf(ymax - ymin, 0.f);
            float iou = inter / (iA + aA - inter);
            if (iou > 0.5f) k0 = 0;
          }
          if (has1 && k1 && r1 > i) {
            float xmin = fmaxf(ix1, c1x), ymin = fmaxf(iy1, c1y);
            float xmax = fminf(ix2, c2x), ymax = fminf(iy2, c2y);
            float inter = fmaxf(xmax - xmin, 0.f) * fmaxf(ymax - ymin, 0.f);
            float iou = inter / (iA + cA - inter);
            if (iou > 0.5f) k1 = 0;
          }
        }
      }
      keep[r0] = k0;
      if (has1) keep[r1] = k1;
    }
    __syncthreads();

    if (r < TOPK) {
      int o = bb * TOPK + r;
      bool kp = keep[r] != 0;
      out[o] = kp ? sc[r] : 0.f;                                  // scores
      out[NBATCH * TOPK + o] = kp ? (float)cls_s[r] : 0.f;        // classes
      float* ob = out + 2 * NBATCH * TOPK + (size_t)o * 4;        // boxes
      ob[0] = kp ? bx1[r] : 0.f;
      ob[1] = kp ? by1[r] : 0.f;
      ob[2] = kp ? bx2[r] : 0.f;
      ob[3] = kp ? by2[r] : 0.f;
      out[6 * NBATCH * TOPK + o] = kp ? 1.f : 0.f;                // keep
    }
  }
}

extern "C" void kernel_launch(void* const* d_in, const int* in_sizes, int n_in,
                              void* d_out, int out_size, void* d_ws, size_t ws_size,
                              hipStream_t stream) {
  Ptrs p;
  // setup_inputs() dict order is INTERLEAVED: cls0, reg0, cls1, reg1, ...
  for (int i = 0; i < 8; ++i) {
    p.cls[i] = (const float*)d_in[2 * i];
    p.reg[i] = (const float*)d_in[2 * i + 1];
  }
  uint16_t* hist    = (uint16_t*)d_ws;                           // 32*32*256*2 = 524,288 B
  uint32_t* counter = (uint32_t*)((char*)d_ws + 524288);         // 128 B
  unsigned long long* cand =
      (unsigned long long*)((char*)d_ws + 524416);               // 32*2048*8 = 524,288 B
  float* out = (float*)d_out;                                    // total ws ≈ 1.05 MB

  void* args[] = { (void*)&p, (void*)&hist, (void*)&counter, (void*)&cand, (void*)&out };
  hipLaunchCooperativeKernel((void*)lffd_all, dim3(GRID), dim3(256), args, 0, stream);
}

// Round 9
// 74.048 us; speedup vs baseline: 3.7976x; 3.7976x over previous
//
#include <hip/hip_runtime.h>
#include <stdint.h>

#define N_ANCH 65648
#define NCHUNK 65          // chunks of 1024 anchors
#define CHUNK  1024
#define CAP    2048        // per-batch candidate list capacity
#define KBASE  0xBE800000u // sortable key of 0.25; fg scores >= 1/3 -> bins in [42,255]
#define NBATCH 32
#define TOPK   100
#define FT     512         // k_final threads

struct Ptrs { const float* cls[8]; const float* reg[8]; };

__constant__ int   c_off[9] = {0,25281,50562,56803,63044,64565,64926,65287,65648};
__constant__ int   c_sz[8]  = {159,159,79,79,39,19,19,19};
__constant__ float c_st[8]  = {4.f,4.f,8.f,8.f,16.f,32.f,32.f,32.f};
__constant__ float c_rf[8]  = {27.5f,35.5f,55.5f,71.5f,111.5f,191.5f,255.5f,319.5f};

// sortable key for the masked score of anchor n in batch b; 0 if background.
// EXACT same fp sequence as all passing rounds.
__device__ inline uint32_t anchor_key(const Ptrs& p, int b, int n) {
  int k = 0;
#pragma unroll
  for (int q = 1; q < 8; ++q) if (n >= c_off[q]) k = q;
  int local = n - c_off[k];
  int hw = c_sz[k] * c_sz[k];
  const float* c = p.cls[k] + (size_t)(b * 3) * hw + local;
  float l0 = c[0], l1 = c[(size_t)hw], l2 = c[(size_t)2 * hw];
  float m = l0; int cl = 0;
  if (l1 > m) { m = l1; cl = 1; }
  if (l2 > m) { m = l2; cl = 2; }
  if (cl == 0) return 0u;
  float s = 1.0f / (expf(l0 - m) + expf(l1 - m) + expf(l2 - m));
  return __float_as_uint(s) | 0x80000000u; // positive float -> monotonic uint
}

// K1 (WIDE, 2080 blocks): exact u32 key per anchor (coalesced) + per-chunk u16 hist
__global__ __launch_bounds__(256) void k_keys(Ptrs p, uint32_t* keys, uint16_t* hist,
                                              uint32_t* counter) {
  int bid = blockIdx.x;
  int b = bid / NCHUNK, chunk = bid % NCHUNK;
  int t = threadIdx.x;
  __shared__ uint32_t lh[256];
  lh[t] = 0;
  if (chunk == 0 && t == 0) counter[b] = 0;   // ordered before K2 by kernel boundary
  __syncthreads();
  int n_base = chunk * CHUNK;
#pragma unroll
  for (int u = 0; u < 4; ++u) {
    int n = n_base + u * 256 + t;
    if (n < N_ANCH) {
      uint32_t key = anchor_key(p, b, n);
      keys[(size_t)b * N_ANCH + n] = key;
      if (key >= KBASE) atomicAdd(&lh[(key - KBASE) >> 16], 1u);  // LDS only
    }
  }
  __syncthreads();
  hist[((size_t)b * NCHUNK + chunk) * 256 + t] = (uint16_t)lh[t];
}

// K2 (WIDE, 2080 blocks): redundant per-block threshold; block-aggregated
// compaction into a contiguous per-batch list (ONE global atomic per block).
__global__ __launch_bounds__(256) void k_collect(const uint32_t* keys, const uint16_t* hist,
                                                 uint32_t* counter, unsigned long long* cand) {
  int bid = blockIdx.x;
  int b = bid / NCHUNK, chunk = bid % NCHUNK;
  int t = threadIdx.x;
  __shared__ uint32_t tot[256];
  __shared__ int s_thr;
  __shared__ uint32_t s_cnt, s_base;
  __shared__ unsigned long long stage[CHUNK];
  const uint16_t* hb = hist + (size_t)b * NCHUNK * 256;
  uint32_t v = 0;
  for (int ch = 0; ch < NCHUNK; ++ch) v += hb[ch * 256 + t];   // coalesced, L2-warm
  tot[t] = v;
  if (t == 0) s_cnt = 0;
  __syncthreads();
  for (int d = 1; d < 256; d <<= 1) {          // inclusive suffix sum
    uint32_t add = (t + d < 256) ? tot[t + d] : 0u;
    __syncthreads();
    tot[t] += add;
    __syncthreads();
  }
  uint32_t suf = tot[t], sufn = (t < 255) ? tot[t + 1] : 0u;
  if (suf >= TOPK && sufn < TOPK) s_thr = t;   // exactly one setter
  if (t == 0 && tot[0] < TOPK) s_thr = 0;
  __syncthreads();
  int thr = s_thr; if (thr < 1) thr = 1;       // bin>=1 <=> foreground
  uint32_t thkey = KBASE + ((uint32_t)thr << 16);  // bin(key)>=thr <=> key>=thkey

  int n_base = chunk * CHUNK;
#pragma unroll
  for (int u = 0; u < 4; ++u) {
    int n = n_base + u * 256 + t;
    if (n < N_ANCH) {
      uint32_t key = keys[(size_t)b * N_ANCH + n];   // coalesced
      if (key >= thkey) {
        uint32_t pos = atomicAdd(&s_cnt, 1u);        // LDS; pos < CHUNK always
        stage[pos] = ((unsigned long long)key << 32) | (uint32_t)(~(uint32_t)n);
      }
    }
  }
  __syncthreads();
  if (t == 0) s_base = atomicAdd(&counter[b], s_cnt);  // one global atomic per block
  __syncthreads();
  uint32_t cnt = s_cnt, base = s_base;
  for (uint32_t j = t; j < cnt; j += 256) {
    uint32_t g = base + j;
    if (g < CAP) cand[(size_t)b * CAP + g] = stage[j]; // coalesced
  }
}

// rank-selection with 8-deep batched LDS broadcast reads (pipelined, latency-hidden).
// s_all must be zero-padded to a multiple of 8 (zeros never outrank real keys).
template<int U>
__device__ inline void rank_select(const unsigned long long* s_all, int c, int c8, int t,
                                   unsigned long long* top) {
  unsigned long long mine[U]; int rk[U];
#pragma unroll
  for (int u = 0; u < U; ++u) {
    int i = t + u * FT;
    mine[u] = (i < c) ? s_all[i] : 0ull;
    rk[u] = 0;
  }
  for (int j = 0; j < c8; j += 8) {
    unsigned long long v0 = s_all[j+0], v1 = s_all[j+1], v2 = s_all[j+2], v3 = s_all[j+3];
    unsigned long long v4 = s_all[j+4], v5 = s_all[j+5], v6 = s_all[j+6], v7 = s_all[j+7];
#pragma unroll
    for (int u = 0; u < U; ++u) {
      rk[u] += (v0 > mine[u]) + (v1 > mine[u]) + (v2 > mine[u]) + (v3 > mine[u])
             + (v4 > mine[u]) + (v5 > mine[u]) + (v6 > mine[u]) + (v7 > mine[u]);
    }
  }
#pragma unroll
  for (int u = 0; u < U; ++u) {
    int i = t + u * FT;
    if (i < c && rk[u] < TOPK) top[rk[u]] = mine[u];   // unique u64s -> unique ranks
  }
}

// K3: one block per batch (512 thr = 8 waves for latency interleave), strictly O(c).
__global__ __launch_bounds__(FT) void k_final(Ptrs p, const uint32_t* counter,
                                              const unsigned long long* cand, float* out) {
  int b = blockIdx.x, t = threadIdx.x;
  __shared__ unsigned long long s_all[CAP + 8];
  __shared__ unsigned long long top[TOPK];
  __shared__ float bx1[TOPK], by1[TOPK], bx2[TOPK], by2[TOPK], area[TOPK], sc[TOPK];
  __shared__ int cls_s[TOPK], keep[TOPK];

  int c = (int)min(counter[b], (uint32_t)CAP);
  int c8 = (c + 7) & ~7;
  for (int i = t; i < c; i += FT) s_all[i] = cand[(size_t)b * CAP + i]; // coalesced
  for (int i = c + t; i < c8; i += FT) s_all[i] = 0ull;                 // pad
  if (t < TOPK) top[t] = 0ull;
  __syncthreads();

  if      (c <= FT)     rank_select<1>(s_all, c, c8, t, top);
  else if (c <= 2 * FT) rank_select<2>(s_all, c, c8, t, top);
  else                  rank_select<4>(s_all, c, c8, t, top);
  __syncthreads();

  // decode top-100
  int r = t;
  if (r < TOPK) {
    unsigned long long pk = top[r];
    if (pk == 0ull) {
      sc[r] = -1.f; cls_s[r] = 0; keep[r] = 0;
      bx1[r] = by1[r] = bx2[r] = by2[r] = 0.f; area[r] = 1.f;
    } else {
      uint32_t key = (uint32_t)(pk >> 32);
      int n = (int)(~(uint32_t)pk);
      float score = __uint_as_float(key & 0x7FFFFFFFu);
      int k2 = 0;
#pragma unroll
      for (int q = 1; q < 8; ++q) if (n >= c_off[q]) k2 = q;
      int local = n - c_off[k2];
      int w = c_sz[k2], hw = w * w;
      int i2 = local / w, j2 = local % w;
      const float* cp = p.cls[k2] + (size_t)(b * 3) * hw + local;
      float l0 = cp[0], l1 = cp[(size_t)hw], l2 = cp[(size_t)2 * hw];
      float m = l0; int cl = 0;
      if (l1 > m) { m = l1; cl = 1; }
      if (l2 > m) { m = l2; cl = 2; }
      const float* rp = p.reg[k2] + (size_t)(b * 4) * hw + local;
      float r0 = rp[0], r1 = rp[(size_t)hw], r2 = rp[(size_t)2 * hw], r3 = rp[(size_t)3 * hw];
      float st = c_st[k2], rf = c_rf[k2];
      float cx = (float)j2 * st + st * 0.5f;
      float cy = (float)i2 * st + st * 0.5f;
      float x1 = cx - r0 * rf, y1 = cy - r1 * rf;
      float x2 = cx + r2 * rf, y2 = cy + r3 * rf;
      sc[r] = score; cls_s[r] = cl;
      bx1[r] = x1; by1[r] = y1; bx2[r] = x2; by2[r] = y2;
      area[r] = (x2 - x1 + 1.0f) * (y2 - y1 + 1.0f);
      keep[r] = (score >= 0.35f && cl > 0) ? 1 : 0;
    }
  }
  __syncthreads();

  // greedy NMS in a single wave: lane l owns ranks l and l+64; zero barriers
  if (t < 64) {
    int r0 = t, r1 = t + 64;
    float a1x = bx1[r0], a1y = by1[r0], a2x = bx2[r0], a2y = by2[r0], aA = area[r0];
    int k0 = keep[r0];
    bool has1 = (r1 < TOPK);
    float c1x = 0.f, c1y = 0.f, c2x = 0.f, c2y = 0.f, cA = 1.f;
    int k1 = 0;
    if (has1) { c1x = bx1[r1]; c1y = by1[r1]; c2x = bx2[r1]; c2y = by2[r1]; cA = area[r1]; k1 = keep[r1]; }
    for (int i = 0; i < TOPK; ++i) {
      int ol = i & 63, sl = i >> 6;
      int   ki  = __shfl(sl ? k1  : k0,  ol);
      float ix1 = __shfl(sl ? c1x : a1x, ol);
      float iy1 = __shfl(sl ? c1y : a1y, ol);
      float ix2 = __shfl(sl ? c2x : a2x, ol);
      float iy2 = __shfl(sl ? c2y : a2y, ol);
      float iA  = __shfl(sl ? cA  : aA,  ol);
      if (ki) {
        if (k0 && r0 > i) {
          float xmin = fmaxf(ix1, a1x), ymin = fmaxf(iy1, a1y);
          float xmax = fminf(ix2, a2x), ymax = fminf(iy2, a2y);
          float inter = fmaxf(xmax - xmin, 0.f) * fmaxf(ymax - ymin, 0.f);
          float iou = inter / (iA + aA - inter);
          if (iou > 0.5f) k0 = 0;
        }
        if (has1 && k1 && r1 > i) {
          float xmin = fmaxf(ix1, c1x), ymin = fmaxf(iy1, c1y);
          float xmax = fminf(ix2, c2x), ymax = fminf(iy2, c2y);
          float inter = fmaxf(xmax - xmin, 0.f) * fmaxf(ymax - ymin, 0.f);
          float iou = inter / (iA + cA - inter);
          if (iou > 0.5f) k1 = 0;
        }
      }
    }
    keep[r0] = k0;
    if (has1) keep[r1] = k1;
  }
  __syncthreads();

  if (r < TOPK) {
    int o = b * TOPK + r;
    bool kp = keep[r] != 0;
    out[o] = kp ? sc[r] : 0.f;                                  // scores
    out[NBATCH * TOPK + o] = kp ? (float)cls_s[r] : 0.f;        // classes
    float* ob = out + 2 * NBATCH * TOPK + (size_t)o * 4;        // boxes
    ob[0] = kp ? bx1[r] : 0.f;
    ob[1] = kp ? by1[r] : 0.f;
    ob[2] = kp ? bx2[r] : 0.f;
    ob[3] = kp ? by2[r] : 0.f;
    out[6 * NBATCH * TOPK + o] = kp ? 1.f : 0.f;                // keep
  }
}

extern "C" void kernel_launch(void* const* d_in, const int* in_sizes, int n_in,
                              void* d_out, int out_size, void* d_ws, size_t ws_size,
                              hipStream_t stream) {
  Ptrs p;
  // setup_inputs() dict order is INTERLEAVED: cls0, reg0, cls1, reg1, ...
  for (int i = 0; i < 8; ++i) {
    p.cls[i] = (const float*)d_in[2 * i];
    p.reg[i] = (const float*)d_in[2 * i + 1];
  }
  uint32_t* keys    = (uint32_t*)d_ws;                           // 32*65648*4  = 8,402,944 B
  uint16_t* hist    = (uint16_t*)((char*)d_ws + 8402944);        // 32*65*256*2 = 1,064,960 B
  uint32_t* counter = (uint32_t*)((char*)d_ws + 9467904);        // 128 B
  unsigned long long* cand =
      (unsigned long long*)((char*)d_ws + 9468032);              // 32*2048*8   = 524,288 B
  float* out = (float*)d_out;                                    // total ws ≈ 10 MB

  k_keys<<<NBATCH * NCHUNK, 256, 0, stream>>>(p, keys, hist, counter);
  k_collect<<<NBATCH * NCHUNK, 256, 0, stream>>>(keys, hist, counter, cand);
  k_final<<<NBATCH, FT, 0, stream>>>(p, counter, cand, out);
}

// Round 10
// 57.798 us; speedup vs baseline: 4.8653x; 1.2811x over previous
//
#include <hip/hip_runtime.h>
#include <stdint.h>

#define N_ANCH 65648
#define NQUAD  (N_ANCH / 4)   // 16412
#define NCHUNK 65             // chunks of 1024 anchors (k_keys)
#define CHUNK  1024
#define CAP    2048           // per-batch candidate capacity (LDS)
#define KBASE  0xBE800000u    // sortable key of 0.25; fg scores >= 1/3 -> bins in [42,255]
#define NBATCH 32
#define TOPK   100
#define FT     1024           // k_final threads (16 waves to hide L2/LDS latency)

struct Ptrs { const float* cls[8]; const float* reg[8]; };

__constant__ int   c_off[9] = {0,25281,50562,56803,63044,64565,64926,65287,65648};
__constant__ int   c_sz[8]  = {159,159,79,79,39,19,19,19};
__constant__ float c_st[8]  = {4.f,4.f,8.f,8.f,16.f,32.f,32.f,32.f};
__constant__ float c_rf[8]  = {27.5f,35.5f,55.5f,71.5f,111.5f,191.5f,255.5f,319.5f};

// sortable key for the masked score of anchor n in batch b; 0 if background.
// EXACT same fp sequence as all passing rounds.
__device__ inline uint32_t anchor_key(const Ptrs& p, int b, int n) {
  int k = 0;
#pragma unroll
  for (int q = 1; q < 8; ++q) if (n >= c_off[q]) k = q;
  int local = n - c_off[k];
  int hw = c_sz[k] * c_sz[k];
  const float* c = p.cls[k] + (size_t)(b * 3) * hw + local;
  float l0 = c[0], l1 = c[(size_t)hw], l2 = c[(size_t)2 * hw];
  float m = l0; int cl = 0;
  if (l1 > m) { m = l1; cl = 1; }
  if (l2 > m) { m = l2; cl = 2; }
  if (cl == 0) return 0u;
  float s = 1.0f / (expf(l0 - m) + expf(l1 - m) + expf(l2 - m));
  return __float_as_uint(s) | 0x80000000u; // positive float -> monotonic uint
}

// K1 (WIDE, 2080 blocks): exact u32 key per anchor (coalesced) + per-chunk u16 hist
__global__ __launch_bounds__(256) void k_keys(Ptrs p, uint32_t* keys, uint16_t* hist) {
  int bid = blockIdx.x;
  int b = bid / NCHUNK, chunk = bid % NCHUNK;
  int t = threadIdx.x;
  __shared__ uint32_t lh[256];
  lh[t] = 0;
  __syncthreads();
  int n_base = chunk * CHUNK;
#pragma unroll
  for (int u = 0; u < 4; ++u) {
    int n = n_base + u * 256 + t;
    if (n < N_ANCH) {
      uint32_t key = anchor_key(p, b, n);
      keys[(size_t)b * N_ANCH + n] = key;
      if (key >= KBASE) atomicAdd(&lh[(key - KBASE) >> 16], 1u);  // LDS only
    }
  }
  __syncthreads();
  hist[((size_t)b * NCHUNK + chunk) * 256 + t] = (uint16_t)lh[t];
}

// rank-selection with 8-deep batched LDS broadcast reads; s_all zero-padded to
// a multiple of 8 (zeros never outrank real keys).
template<int U>
__device__ inline void rank_select(const unsigned long long* s_all, int c, int c8, int t,
                                   unsigned long long* top) {
  unsigned long long mine[U]; int rk[U];
#pragma unroll
  for (int u = 0; u < U; ++u) {
    int i = t + u * FT;
    mine[u] = (i < c) ? s_all[i] : 0ull;
    rk[u] = 0;
  }
  for (int j = 0; j < c8; j += 8) {
    unsigned long long v0 = s_all[j+0], v1 = s_all[j+1], v2 = s_all[j+2], v3 = s_all[j+3];
    unsigned long long v4 = s_all[j+4], v5 = s_all[j+5], v6 = s_all[j+6], v7 = s_all[j+7];
#pragma unroll
    for (int u = 0; u < U; ++u) {
      rk[u] += (v0 > mine[u]) + (v1 > mine[u]) + (v2 > mine[u]) + (v3 > mine[u])
             + (v4 > mine[u]) + (v5 > mine[u]) + (v6 > mine[u]) + (v7 > mine[u]);
    }
  }
#pragma unroll
  for (int u = 0; u < U; ++u) {
    int i = t + u * FT;
    if (i < c && rk[u] < TOPK) top[rk[u]] = mine[u];   // unique u64s -> unique ranks
  }
}

// K2: one block per batch, 1024 threads. Hist reduce + threshold + coalesced key
// scan + LDS collect + rank-select + decode + single-wave NMS + out.
__global__ __launch_bounds__(FT) void k_final(Ptrs p, const uint32_t* keys,
                                              const uint16_t* hist, float* out) {
  int b = blockIdx.x, t = threadIdx.x;
  __shared__ uint32_t part[4][256];
  __shared__ uint32_t tot[256];
  __shared__ unsigned long long s_all[CAP + 8];
  __shared__ unsigned long long top[TOPK];
  __shared__ float bx1[TOPK], by1[TOPK], bx2[TOPK], by2[TOPK], area[TOPK], sc[TOPK];
  __shared__ int cls_s[TOPK], keep[TOPK];
  __shared__ uint32_t s_cnt;
  __shared__ int s_thr;

  // ---- threshold from per-chunk hists (4-way parallel reduce over 65 chunks) ----
  {
    const uint16_t* hb = hist + (size_t)b * NCHUNK * 256;
    int g = t >> 8, tb = t & 255;
    uint32_t v = 0;
    for (int ch = g; ch < NCHUNK; ch += 4) v += hb[ch * 256 + tb];
    part[g][tb] = v;
    if (t == 0) s_cnt = 0;
    if (t < TOPK) top[t] = 0ull;
    __syncthreads();
    if (t < 256) tot[t] = part[0][t] + part[1][t] + part[2][t] + part[3][t];
    __syncthreads();
    for (int d = 1; d < 256; d <<= 1) {            // inclusive suffix sum
      uint32_t add = 0;
      if (t < 256 && t + d < 256) add = tot[t + d];
      __syncthreads();
      if (t < 256) tot[t] += add;
      __syncthreads();
    }
    if (t < 256) {
      uint32_t suf = tot[t], sufn = (t < 255) ? tot[t + 1] : 0u;
      if (suf >= TOPK && sufn < TOPK) s_thr = t;   // exactly one setter
      if (t == 0 && tot[0] < TOPK) s_thr = 0;
    }
    __syncthreads();
  }
  int thr = s_thr; if (thr < 1) thr = 1;           // bin>=1 <=> foreground
  uint32_t thkey = KBASE + ((uint32_t)thr << 16);  // bin(key)>=thr <=> key>=thkey

  // ---- scan this batch's keys (256 KB, coalesced uint4) and collect to LDS ----
  {
    const uint4* kp4 = (const uint4*)(keys + (size_t)b * N_ANCH);
    for (int i = t; i < NQUAD; i += FT) {
      uint4 kv = kp4[i];
      int n0 = i * 4;
      if (kv.x >= thkey) { uint32_t q = atomicAdd(&s_cnt, 1u); if (q < CAP) s_all[q] = ((unsigned long long)kv.x << 32) | (uint32_t)(~(uint32_t)(n0 + 0)); }
      if (kv.y >= thkey) { uint32_t q = atomicAdd(&s_cnt, 1u); if (q < CAP) s_all[q] = ((unsigned long long)kv.y << 32) | (uint32_t)(~(uint32_t)(n0 + 1)); }
      if (kv.z >= thkey) { uint32_t q = atomicAdd(&s_cnt, 1u); if (q < CAP) s_all[q] = ((unsigned long long)kv.z << 32) | (uint32_t)(~(uint32_t)(n0 + 2)); }
      if (kv.w >= thkey) { uint32_t q = atomicAdd(&s_cnt, 1u); if (q < CAP) s_all[q] = ((unsigned long long)kv.w << 32) | (uint32_t)(~(uint32_t)(n0 + 3)); }
    }
  }
  __syncthreads();
  int c = (int)min(s_cnt, (uint32_t)CAP);
  int c8 = (c + 7) & ~7;
  for (int i = c + t; i < c8; i += FT) s_all[i] = 0ull;   // pad
  __syncthreads();

  if (c <= FT) rank_select<1>(s_all, c, c8, t, top);
  else         rank_select<2>(s_all, c, c8, t, top);
  __syncthreads();

  // ---- decode top-100 ----
  int r = t;
  if (r < TOPK) {
    unsigned long long pk = top[r];
    if (pk == 0ull) {
      sc[r] = -1.f; cls_s[r] = 0; keep[r] = 0;
      bx1[r] = by1[r] = bx2[r] = by2[r] = 0.f; area[r] = 1.f;
    } else {
      uint32_t key = (uint32_t)(pk >> 32);
      int n = (int)(~(uint32_t)pk);
      float score = __uint_as_float(key & 0x7FFFFFFFu);
      int k2 = 0;
#pragma unroll
      for (int q = 1; q < 8; ++q) if (n >= c_off[q]) k2 = q;
      int local = n - c_off[k2];
      int w = c_sz[k2], hw = w * w;
      int i2 = local / w, j2 = local % w;
      const float* cp = p.cls[k2] + (size_t)(b * 3) * hw + local;
      float l0 = cp[0], l1 = cp[(size_t)hw], l2 = cp[(size_t)2 * hw];
      float m = l0; int cl = 0;
      if (l1 > m) { m = l1; cl = 1; }
      if (l2 > m) { m = l2; cl = 2; }
      const float* rp = p.reg[k2] + (size_t)(b * 4) * hw + local;
      float r0 = rp[0], r1 = rp[(size_t)hw], r2 = rp[(size_t)2 * hw], r3 = rp[(size_t)3 * hw];
      float st = c_st[k2], rf = c_rf[k2];
      float cx = (float)j2 * st + st * 0.5f;
      float cy = (float)i2 * st + st * 0.5f;
      float x1 = cx - r0 * rf, y1 = cy - r1 * rf;
      float x2 = cx + r2 * rf, y2 = cy + r3 * rf;
      sc[r] = score; cls_s[r] = cl;
      bx1[r] = x1; by1[r] = y1; bx2[r] = x2; by2[r] = y2;
      area[r] = (x2 - x1 + 1.0f) * (y2 - y1 + 1.0f);
      keep[r] = (score >= 0.35f && cl > 0) ? 1 : 0;
    }
  }
  __syncthreads();

  // ---- greedy NMS in a single wave: lane l owns ranks l and l+64 ----
  if (t < 64) {
    int r0 = t, r1 = t + 64;
    float a1x = bx1[r0], a1y = by1[r0], a2x = bx2[r0], a2y = by2[r0], aA = area[r0];
    int k0 = keep[r0];
    bool has1 = (r1 < TOPK);
    float c1x = 0.f, c1y = 0.f, c2x = 0.f, c2y = 0.f, cA = 1.f;
    int k1 = 0;
    if (has1) { c1x = bx1[r1]; c1y = by1[r1]; c2x = bx2[r1]; c2y = by2[r1]; cA = area[r1]; k1 = keep[r1]; }
    for (int i = 0; i < TOPK; ++i) {
      int ol = i & 63, sl = i >> 6;
      int   ki  = __shfl(sl ? k1  : k0,  ol);
      float ix1 = __shfl(sl ? c1x : a1x, ol);
      float iy1 = __shfl(sl ? c1y : a1y, ol);
      float ix2 = __shfl(sl ? c2x : a2x, ol);
      float iy2 = __shfl(sl ? c2y : a2y, ol);
      float iA  = __shfl(sl ? cA  : aA,  ol);
      if (ki) {
        if (k0 && r0 > i) {
          float xmin = fmaxf(ix1, a1x), ymin = fmaxf(iy1, a1y);
          float xmax = fminf(ix2, a2x), ymax = fminf(iy2, a2y);
          float inter = fmaxf(xmax - xmin, 0.f) * fmaxf(ymax - ymin, 0.f);
          float iou = inter / (iA + aA - inter);
          if (iou > 0.5f) k0 = 0;
        }
        if (has1 && k1 && r1 > i) {
          float xmin = fmaxf(ix1, c1x), ymin = fmaxf(iy1, c1y);
          float xmax = fminf(ix2, c2x), ymax = fminf(iy2, c2y);
          float inter = fmaxf(xmax - xmin, 0.f) * fmaxf(ymax - ymin, 0.f);
          float iou = inter / (iA + cA - inter);
          if (iou > 0.5f) k1 = 0;
        }
      }
    }
    keep[r0] = k0;
    if (has1) keep[r1] = k1;
  }
  __syncthreads();

  if (r < TOPK) {
    int o = b * TOPK + r;
    bool kp = keep[r] != 0;
    out[o] = kp ? sc[r] : 0.f;                                  // scores
    out[NBATCH * TOPK + o] = kp ? (float)cls_s[r] : 0.f;        // classes
    float* ob = out + 2 * NBATCH * TOPK + (size_t)o * 4;        // boxes
    ob[0] = kp ? bx1[r] : 0.f;
    ob[1] = kp ? by1[r] : 0.f;
    ob[2] = kp ? bx2[r] : 0.f;
    ob[3] = kp ? by2[r] : 0.f;
    out[6 * NBATCH * TOPK + o] = kp ? 1.f : 0.f;                // keep
  }
}

extern "C" void kernel_launch(void* const* d_in, const int* in_sizes, int n_in,
                              void* d_out, int out_size, void* d_ws, size_t ws_size,
                              hipStream_t stream) {
  Ptrs p;
  // setup_inputs() dict order is INTERLEAVED: cls0, reg0, cls1, reg1, ...
  for (int i = 0; i < 8; ++i) {
    p.cls[i] = (const float*)d_in[2 * i];
    p.reg[i] = (const float*)d_in[2 * i + 1];
  }
  uint32_t* keys = (uint32_t*)d_ws;                              // 32*65648*4  = 8,402,944 B
  uint16_t* hist = (uint16_t*)((char*)d_ws + 8402944);           // 32*65*256*2 = 1,064,960 B
  float* out = (float*)d_out;                                    // total ws ≈ 9.5 MB

  k_keys<<<NBATCH * NCHUNK, 256, 0, stream>>>(p, keys, hist);
  k_final<<<NBATCH, FT, 0, stream>>>(p, keys, hist, out);
}